// Round 3
// baseline (519.040 us; speedup 1.0000x reference)
//
#include <hip/hip_runtime.h>

#define LN_EPS 1e-5f

constexpr int KDIM = 192;
constexpr int NOUT = 256;
constexpr int ROWS_PER_BLOCK = 32;   // FC kernel tile
constexpr int ROWS_PER_WAVE  = 8;

// ---------------------------------------------------------------------------
// Kernel A (v3): gather + pool.  One wave per row, float4 wide-gather pooling.
// Per pooled feature: lane l -> pooled-row slot j = l>>3, float4 chunk fc = l&7.
// Each gather instruction fetches 8 distinct table rows x 128 B = 1 KB, fully
// used.  All indices preloaded -> all gathers independent / in flight at once.
// ---------------------------------------------------------------------------
__global__ __launch_bounds__(256)
void ut_gather_kernel(const int*   __restrict__ user_input,
                      const float* __restrict__ emb,
                      const int*   __restrict__ sc_country_idx,
                      const float* __restrict__ sc_country_emb,
                      const int*   __restrict__ sc_device_idx,
                      const float* __restrict__ sc_device_emb,
                      const int*   __restrict__ mf_tags_idx,
                      const float* __restrict__ mf_tags_emb,
                      const int*   __restrict__ mf_history_idx,
                      const float* __restrict__ mf_history_emb,
                      float*       __restrict__ X,
                      int B)
{
    const int lane = threadIdx.x & 63;
    const int wave = threadIdx.x >> 6;
    const int row  = blockIdx.x * 4 + wave;
    if (row >= B) return;                       // wave-uniform exit

    const int half = lane >> 5;                 // 0 or 1
    const int col  = lane & 31;                 // 0..31
    const int jt   = lane >> 3;                 // pooled-row slot 0..7
    const int fc   = lane & 7;                  // float4 chunk 0..7

    const int u = __builtin_amdgcn_readfirstlane(user_input[row]);
    float* __restrict__ Xr = X + (size_t)row * KDIM;

    // ---- preload all indices (independent) ----
    const int ci = sc_country_idx[u];
    const int di = sc_device_idx[u];

    const int* __restrict__ tp = mf_tags_idx    + (size_t)u * 20;
    const int* __restrict__ hp = mf_history_idx + (size_t)u * 50;

    int  ti[3];  bool tv[3];
    #pragma unroll
    for (int p = 0; p < 3; ++p) {
        const int j = p * 8 + jt;
        tv[p] = (j < 20);
        ti[p] = tv[p] ? tp[j] : 0;
    }
    int  hi[7];  bool hv[7];
    #pragma unroll
    for (int p = 0; p < 7; ++p) {
        const int j = p * 8 + jt;
        hv[p] = (j < 50);
        hi[p] = hv[p] ? hp[j] : 0;
    }

    // ---- main embedding: 64 floats, one per lane (256 B coalesced) ----
    const float e = emb[(size_t)u * 64 + lane];

    // ---- scalar side features ----
    const float sc = (half == 0) ? sc_country_emb[ci * 32 + col]
                                 : sc_device_emb [di * 32 + col];

    // ---- pooled gathers: all independent, 1 KB useful bytes per instr ----
    float4 ta4 = make_float4(0.f, 0.f, 0.f, 0.f);
    #pragma unroll
    for (int p = 0; p < 3; ++p) {
        const float4 g = *(const float4*)&mf_tags_emb[(size_t)ti[p] * 32 + fc * 4];
        if (tv[p]) { ta4.x += g.x; ta4.y += g.y; ta4.z += g.z; ta4.w += g.w; }
    }
    float4 ha4 = make_float4(0.f, 0.f, 0.f, 0.f);
    #pragma unroll
    for (int p = 0; p < 7; ++p) {
        const float4 g = *(const float4*)&mf_history_emb[(size_t)hi[p] * 32 + fc * 4];
        if (hv[p]) { ha4.x += g.x; ha4.y += g.y; ha4.z += g.z; ha4.w += g.w; }
    }

    // ---- butterfly reduce across the 8 j-slots (lane bits 3,4,5) ----
    #pragma unroll
    for (int m = 8; m <= 32; m <<= 1) {
        ta4.x += __shfl_xor(ta4.x, m, 64);  ta4.y += __shfl_xor(ta4.y, m, 64);
        ta4.z += __shfl_xor(ta4.z, m, 64);  ta4.w += __shfl_xor(ta4.w, m, 64);
        ha4.x += __shfl_xor(ha4.x, m, 64);  ha4.y += __shfl_xor(ha4.y, m, 64);
        ha4.z += __shfl_xor(ha4.z, m, 64);  ha4.w += __shfl_xor(ha4.w, m, 64);
    }

    // ---- write the 192-float row ----
    Xr[lane] = e;                                   // cols 0..63
    if (half == 0) Xr[64 + col] = sc;               // country: 64..95
    else           Xr[96 + col] = sc;               // device:  96..127
    if (lane < 8) {
        const float s_t = 1.f / 20.f, s_h = 1.f / 50.f;
        float4 t = make_float4(ta4.x * s_t, ta4.y * s_t, ta4.z * s_t, ta4.w * s_t);
        float4 h = make_float4(ha4.x * s_h, ha4.y * s_h, ha4.z * s_h, ha4.w * s_h);
        *(float4*)&Xr[128 + lane * 4] = t;          // tags:    128..159
        *(float4*)&Xr[160 + lane * 4] = h;          // history: 160..191
    }
}

// ---------------------------------------------------------------------------
// Kernel B: FC 192->256 + ReLU + LayerNorm.  (UNCHANGED from Round 2 —
// differential experiment: any dur_us delta is attributable to the gather.)
// ---------------------------------------------------------------------------
__global__ __launch_bounds__(256)
void ut_fc_ln_kernel(const float* __restrict__ Xg,
                     const float* __restrict__ fc_w,
                     const float* __restrict__ fc_b,
                     const float* __restrict__ ln_g,
                     const float* __restrict__ ln_b,
                     float*       __restrict__ out,
                     int B)
{
    __shared__ float X[ROWS_PER_BLOCK][KDIM];   // 24 KB

    const int tid  = threadIdx.x;
    const int lane = tid & 63;
    const int wave = tid >> 6;
    const int row0 = blockIdx.x * ROWS_PER_BLOCK;

    {
        const float4* __restrict__ src = (const float4*)(Xg + (size_t)row0 * KDIM);
        float4* dst = (float4*)&X[0][0];
        #pragma unroll
        for (int i = 0; i < 6; ++i) dst[tid + 256 * i] = src[tid + 256 * i];
    }
    __syncthreads();

    const int c0 = lane;
    float acc[ROWS_PER_WAVE][4];
    float g4[4], b4[4];
    #pragma unroll
    for (int ci = 0; ci < 4; ++ci) {
        const int c = c0 + 64 * ci;
        const float bias = fc_b[c];
        g4[ci] = ln_g[c];
        b4[ci] = ln_b[c];
        #pragma unroll
        for (int ri = 0; ri < ROWS_PER_WAVE; ++ri) acc[ri][ci] = bias;
    }

    for (int kc = 0; kc < KDIM; kc += 4) {
        float4 w[4];
        #pragma unroll
        for (int ci = 0; ci < 4; ++ci)
            w[ci] = *(const float4*)&fc_w[(c0 + 64 * ci) * KDIM + kc];
        #pragma unroll
        for (int ri = 0; ri < ROWS_PER_WAVE; ++ri) {
            const float4 x = *(const float4*)&X[wave * ROWS_PER_WAVE + ri][kc];
            #pragma unroll
            for (int ci = 0; ci < 4; ++ci) {
                acc[ri][ci] += x.x * w[ci].x + x.y * w[ci].y
                             + x.z * w[ci].z + x.w * w[ci].w;
            }
        }
    }

    #pragma unroll
    for (int ri = 0; ri < ROWS_PER_WAVE; ++ri) {
        const int row = row0 + wave * ROWS_PER_WAVE + ri;
        float y[4];
        float s = 0.f, s2 = 0.f;
        #pragma unroll
        for (int ci = 0; ci < 4; ++ci) {
            y[ci] = fmaxf(acc[ri][ci], 0.f);
            s  += y[ci];
            s2 += y[ci] * y[ci];
        }
        #pragma unroll
        for (int m = 32; m >= 1; m >>= 1) {
            s  += __shfl_xor(s,  m, 64);
            s2 += __shfl_xor(s2, m, 64);
        }
        const float mu  = s  * (1.f / 256.f);
        const float var = s2 * (1.f / 256.f) - mu * mu;
        const float rs  = rsqrtf(var + LN_EPS);
        if (row < B) {
            #pragma unroll
            for (int ci = 0; ci < 4; ++ci) {
                const int c = c0 + 64 * ci;
                out[row * NOUT + c] = (y[ci] - mu) * rs * g4[ci] + b4[ci];
            }
        }
    }
}

extern "C" void kernel_launch(void* const* d_in, const int* in_sizes, int n_in,
                              void* d_out, int out_size, void* d_ws, size_t ws_size,
                              hipStream_t stream)
{
    const int*   user_input     = (const int*)  d_in[0];
    const float* emb            = (const float*)d_in[1];
    const int*   sc_country_idx = (const int*)  d_in[2];
    const float* sc_country_emb = (const float*)d_in[3];
    const int*   sc_device_idx  = (const int*)  d_in[4];
    const float* sc_device_emb  = (const float*)d_in[5];
    const int*   mf_tags_idx    = (const int*)  d_in[6];
    const float* mf_tags_emb    = (const float*)d_in[7];
    const int*   mf_history_idx = (const int*)  d_in[8];
    const float* mf_history_emb = (const float*)d_in[9];
    const float* fc_w           = (const float*)d_in[10];
    const float* fc_b           = (const float*)d_in[11];
    const float* ln_g           = (const float*)d_in[12];
    const float* ln_b           = (const float*)d_in[13];
    float*       out            = (float*)d_out;
    float*       X              = (float*)d_ws;     // [B][192], 12.6 MB

    const int B = in_sizes[0];

    const int gatherGrid = (B + 3) / 4;             // 4 rows (waves) per block
    ut_gather_kernel<<<gatherGrid, 256, 0, stream>>>(
        user_input, emb, sc_country_idx, sc_country_emb,
        sc_device_idx, sc_device_emb, mf_tags_idx, mf_tags_emb,
        mf_history_idx, mf_history_emb, X, B);

    const int fcGrid = (B + ROWS_PER_BLOCK - 1) / ROWS_PER_BLOCK;
    ut_fc_ln_kernel<<<fcGrid, 256, 0, stream>>>(
        X, fc_w, fc_b, ln_g, ln_b, out, B);
}

// Round 4
// 465.965 us; speedup vs baseline: 1.1139x; 1.1139x over previous
//
#include <hip/hip_runtime.h>

#define LN_EPS 1e-5f

typedef _Float16 f16;
typedef _Float16 f16x4 __attribute__((ext_vector_type(4)));
typedef _Float16 f16x8 __attribute__((ext_vector_type(8)));
typedef float    f32x4 __attribute__((ext_vector_type(4)));

constexpr int KDIM = 192;
constexpr int NOUT = 256;

// ---------------------------------------------------------------------------
// Kernel W: fc_w fp32 -> f16 (one-time per launch; 49152 elems, 12288 float4)
// ---------------------------------------------------------------------------
__global__ __launch_bounds__(256)
void ut_wconv_kernel(const float* __restrict__ fc_w, f16* __restrict__ W16)
{
    const int i = blockIdx.x * 256 + threadIdx.x;     // 0..12287
    const float4 v = ((const float4*)fc_w)[i];
    f16x4 h = { (f16)v.x, (f16)v.y, (f16)v.z, (f16)v.w };
    ((f16x4*)W16)[i] = h;
}

// ---------------------------------------------------------------------------
// Kernel A: gather + pool (v3 wide-gather structure), writes X as f16.
// One wave per row; pooled gathers fetch 8 distinct table rows x 128 B per
// instruction; all indices preloaded so every gather is in flight at once.
// ---------------------------------------------------------------------------
__global__ __launch_bounds__(256)
void ut_gather_kernel(const int*   __restrict__ user_input,
                      const float* __restrict__ emb,
                      const int*   __restrict__ sc_country_idx,
                      const float* __restrict__ sc_country_emb,
                      const int*   __restrict__ sc_device_idx,
                      const float* __restrict__ sc_device_emb,
                      const int*   __restrict__ mf_tags_idx,
                      const float* __restrict__ mf_tags_emb,
                      const int*   __restrict__ mf_history_idx,
                      const float* __restrict__ mf_history_emb,
                      f16*         __restrict__ X16,
                      int B)
{
    const int lane = threadIdx.x & 63;
    const int wave = threadIdx.x >> 6;
    const int row  = blockIdx.x * 4 + wave;
    if (row >= B) return;                       // wave-uniform exit

    const int half = lane >> 5;                 // 0 or 1
    const int col  = lane & 31;                 // 0..31
    const int jt   = lane >> 3;                 // pooled-row slot 0..7
    const int fc   = lane & 7;                  // float4 chunk 0..7

    const int u = __builtin_amdgcn_readfirstlane(user_input[row]);
    f16* __restrict__ Xr = X16 + (size_t)row * KDIM;

    // ---- preload all indices (independent) ----
    const int ci = sc_country_idx[u];
    const int di = sc_device_idx[u];

    const int* __restrict__ tp = mf_tags_idx    + (size_t)u * 20;
    const int* __restrict__ hp = mf_history_idx + (size_t)u * 50;

    int  ti[3];  bool tv[3];
    #pragma unroll
    for (int p = 0; p < 3; ++p) {
        const int j = p * 8 + jt;
        tv[p] = (j < 20);
        ti[p] = tv[p] ? tp[j] : 0;
    }
    int  hi[7];  bool hv[7];
    #pragma unroll
    for (int p = 0; p < 7; ++p) {
        const int j = p * 8 + jt;
        hv[p] = (j < 50);
        hi[p] = hv[p] ? hp[j] : 0;
    }

    // ---- main embedding: 64 floats, one per lane (256 B coalesced) ----
    const float e = emb[(size_t)u * 64 + lane];

    // ---- scalar side features ----
    const float sc = (half == 0) ? sc_country_emb[ci * 32 + col]
                                 : sc_device_emb [di * 32 + col];

    // ---- pooled gathers: all independent, 1 KB useful bytes per instr ----
    float4 ta4 = make_float4(0.f, 0.f, 0.f, 0.f);
    #pragma unroll
    for (int p = 0; p < 3; ++p) {
        const float4 g = *(const float4*)&mf_tags_emb[(size_t)ti[p] * 32 + fc * 4];
        if (tv[p]) { ta4.x += g.x; ta4.y += g.y; ta4.z += g.z; ta4.w += g.w; }
    }
    float4 ha4 = make_float4(0.f, 0.f, 0.f, 0.f);
    #pragma unroll
    for (int p = 0; p < 7; ++p) {
        const float4 g = *(const float4*)&mf_history_emb[(size_t)hi[p] * 32 + fc * 4];
        if (hv[p]) { ha4.x += g.x; ha4.y += g.y; ha4.z += g.z; ha4.w += g.w; }
    }

    // ---- butterfly reduce across the 8 j-slots (lane bits 3,4,5) ----
    #pragma unroll
    for (int m = 8; m <= 32; m <<= 1) {
        ta4.x += __shfl_xor(ta4.x, m, 64);  ta4.y += __shfl_xor(ta4.y, m, 64);
        ta4.z += __shfl_xor(ta4.z, m, 64);  ta4.w += __shfl_xor(ta4.w, m, 64);
        ha4.x += __shfl_xor(ha4.x, m, 64);  ha4.y += __shfl_xor(ha4.y, m, 64);
        ha4.z += __shfl_xor(ha4.z, m, 64);  ha4.w += __shfl_xor(ha4.w, m, 64);
    }

    // ---- write the 192-element f16 row ----
    Xr[lane] = (f16)e;                              // cols 0..63
    if (half == 0) Xr[64 + col] = (f16)sc;          // country: 64..95
    else           Xr[96 + col] = (f16)sc;          // device:  96..127
    if (lane < 8) {
        const float s_t = 1.f / 20.f, s_h = 1.f / 50.f;
        f16x4 t = { (f16)(ta4.x * s_t), (f16)(ta4.y * s_t),
                    (f16)(ta4.z * s_t), (f16)(ta4.w * s_t) };
        f16x4 h = { (f16)(ha4.x * s_h), (f16)(ha4.y * s_h),
                    (f16)(ha4.z * s_h), (f16)(ha4.w * s_h) };
        *(f16x4*)&Xr[128 + lane * 4] = t;           // tags:    128..159
        *(f16x4*)&Xr[160 + lane * 4] = h;           // history: 160..191
    }
}

// ---------------------------------------------------------------------------
// Kernel B (v4): FC 192->256 via f16 MFMA + ReLU + LayerNorm.
// Block = 256 threads (4 waves) = 16 rows x 256 cols.  Wave w: cols w*64..+63
// as 4 col-tiles of 16.  fc_w is [N][K] = B^T layout -> A and B fragments are
// both contiguous 16B runs along k:  frag[j] = M[lane&15][(lane>>4)*8 + j].
// C/D: col = lane&15, row = (lane>>4)*4 + reg   (m89-verified mapping).
// ---------------------------------------------------------------------------
__global__ __launch_bounds__(256)
void ut_fc_ln_kernel(const f16*   __restrict__ X16,
                     const f16*   __restrict__ W16,
                     const float* __restrict__ fc_b,
                     const float* __restrict__ ln_g,
                     const float* __restrict__ ln_b,
                     float*       __restrict__ out,
                     int B)
{
    __shared__ float sb[4][16];
    __shared__ float s2b[4][16];

    const int tid  = threadIdx.x;
    const int lane = tid & 63;
    const int wave = tid >> 6;
    const int t    = lane & 15;     // frag row/col index
    const int quad = lane >> 4;     // 0..3
    const int row0 = blockIdx.x * 16;
    if (row0 >= B) return;
    const int colbase = wave * 64;

    const f16* __restrict__ arow = X16 + (size_t)(row0 + t) * KDIM + quad * 8;

    f32x4 acc[4];
    #pragma unroll
    for (int ct = 0; ct < 4; ++ct) acc[ct] = (f32x4){0.f, 0.f, 0.f, 0.f};

    #pragma unroll
    for (int kt = 0; kt < 6; ++kt) {            // K = 192 = 6 * 32
        const f16x8 a = *(const f16x8*)(arow + kt * 32);
        #pragma unroll
        for (int ct = 0; ct < 4; ++ct) {
            const f16x8 b = *(const f16x8*)(W16 + (size_t)(colbase + ct * 16 + t) * KDIM
                                                 + kt * 32 + quad * 8);
            acc[ct] = __builtin_amdgcn_mfma_f32_16x16x32_f16(a, b, acc[ct], 0, 0, 0);
        }
    }

    // ---- epilogue: bias + ReLU, LN stats ----
    float bias[4], g4[4], bb4[4];
    #pragma unroll
    for (int ct = 0; ct < 4; ++ct) {
        const int c = colbase + ct * 16 + t;
        bias[ct] = fc_b[c];
        g4[ct]   = ln_g[c];
        bb4[ct]  = ln_b[c];
    }

    float y[4][4];
    float s[4]  = {0.f, 0.f, 0.f, 0.f};
    float s2[4] = {0.f, 0.f, 0.f, 0.f};
    #pragma unroll
    for (int ct = 0; ct < 4; ++ct) {
        #pragma unroll
        for (int r = 0; r < 4; ++r) {
            const float v = fmaxf(acc[ct][r] + bias[ct], 0.f);
            y[ct][r] = v;
            s[r]  += v;
            s2[r] += v * v;
        }
    }
    // reduce across the 16 t-lanes (lane bits 0..3); quad bits untouched
    #pragma unroll
    for (int m = 1; m <= 8; m <<= 1) {
        #pragma unroll
        for (int r = 0; r < 4; ++r) {
            s[r]  += __shfl_xor(s[r],  m, 64);
            s2[r] += __shfl_xor(s2[r], m, 64);
        }
    }
    if (t == 0) {
        #pragma unroll
        for (int r = 0; r < 4; ++r) {
            sb [wave][quad * 4 + r] = s[r];
            s2b[wave][quad * 4 + r] = s2[r];
        }
    }
    __syncthreads();

    #pragma unroll
    for (int r = 0; r < 4; ++r) {
        const int rho = quad * 4 + r;
        const float st  = sb [0][rho] + sb [1][rho] + sb [2][rho] + sb [3][rho];
        const float s2t = s2b[0][rho] + s2b[1][rho] + s2b[2][rho] + s2b[3][rho];
        const float mu  = st  * (1.f / 256.f);
        const float var = s2t * (1.f / 256.f) - mu * mu;
        const float rs  = rsqrtf(var + LN_EPS);
        #pragma unroll
        for (int ct = 0; ct < 4; ++ct) {
            const int c = colbase + ct * 16 + t;
            out[(size_t)(row0 + rho) * NOUT + c] = (y[ct][r] - mu) * rs * g4[ct] + bb4[ct];
        }
    }
}

extern "C" void kernel_launch(void* const* d_in, const int* in_sizes, int n_in,
                              void* d_out, int out_size, void* d_ws, size_t ws_size,
                              hipStream_t stream)
{
    const int*   user_input     = (const int*)  d_in[0];
    const float* emb            = (const float*)d_in[1];
    const int*   sc_country_idx = (const int*)  d_in[2];
    const float* sc_country_emb = (const float*)d_in[3];
    const int*   sc_device_idx  = (const int*)  d_in[4];
    const float* sc_device_emb  = (const float*)d_in[5];
    const int*   mf_tags_idx    = (const int*)  d_in[6];
    const float* mf_tags_emb    = (const float*)d_in[7];
    const int*   mf_history_idx = (const int*)  d_in[8];
    const float* mf_history_emb = (const float*)d_in[9];
    const float* fc_w           = (const float*)d_in[10];
    const float* fc_b           = (const float*)d_in[11];
    const float* ln_g           = (const float*)d_in[12];
    const float* ln_b           = (const float*)d_in[13];
    float*       out            = (float*)d_out;

    f16* X16 = (f16*)d_ws;                               // [B][192] f16 = 6.3 MB
    f16* W16 = (f16*)((char*)d_ws + (size_t)(16 << 20)); // [256][192] f16 = 96 KB

    const int B = in_sizes[0];

    ut_wconv_kernel<<<48, 256, 0, stream>>>(fc_w, W16);  // 12288 float4s

    const int gatherGrid = (B + 3) / 4;                  // 4 rows (waves) per block
    ut_gather_kernel<<<gatherGrid, 256, 0, stream>>>(
        user_input, emb, sc_country_idx, sc_country_emb,
        sc_device_idx, sc_device_emb, mf_tags_idx, mf_tags_emb,
        mf_history_idx, mf_history_emb, X16, B);

    const int fcGrid = (B + 15) / 16;                    // 16 rows per block
    ut_fc_ln_kernel<<<fcGrid, 256, 0, stream>>>(
        X16, W16, fc_b, ln_g, ln_b, out, B);
}